// Round 1
// baseline (132.397 us; speedup 1.0000x reference)
//
#include <hip/hip_runtime.h>

#define HW 16384
#define LDS_W 72   // padded row stride in bf16 elems: 144 B = 9 dwords*4 -> 16B-aligned rows, 2-way-free reads

typedef __attribute__((ext_vector_type(8))) __bf16 bf16x8;
typedef __attribute__((ext_vector_type(4))) float floatx4;
typedef __attribute__((ext_vector_type(4))) unsigned short ushort4_t;
typedef __attribute__((ext_vector_type(8))) unsigned short ushort8_t;

__device__ __forceinline__ unsigned short f2bf(float f) {
    // round-to-nearest-even fp32 -> bf16 (inputs are finite ~N(0,1))
    unsigned int u = __builtin_bit_cast(unsigned int, f);
    unsigned int r = (u + 0x7FFFu + ((u >> 16) & 1u)) >> 16;
    return (unsigned short)r;
}

__global__ void wconv_kernel(const float* __restrict__ w, unsigned short* __restrict__ wb) {
    int i = blockIdx.x * 256 + threadIdx.x;   // 65536 elements total
    wb[i] = f2bf(w[i]);
}

// One block: all 256 output channels x 64 pixels, K=256.
// 4 waves; wave wv owns channel rows {64*g + 16*wv + r : g=0..3, r=0..15} so the
// lifting epilogue (combines q, q+64, q+128, q+192) is lane-local.
__global__ void fused_gemm_lift(const float* __restrict__ x,
                                const unsigned short* __restrict__ wb,
                                const float* __restrict__ lp_v,
                                const float* __restrict__ hp_v,
                                const float* __restrict__ lp_h,
                                const float* __restrict__ hp_h,
                                float* __restrict__ out) {
    __shared__ unsigned short ws_s[256 * LDS_W];  // W tile [o][k], k-innermost
    __shared__ unsigned short xs_s[64 * LDS_W];   // X^T tile [pixel][k], k-innermost

    const int tid  = threadIdx.x;
    const int wv   = tid >> 6;
    const int lane = tid & 63;
    const int tile = blockIdx.x & 255;   // pixel tile within batch
    const int bb   = blockIdx.x >> 8;    // batch index
    const int p0   = tile * 64;

    const float* xb = x + (size_t)bb * 256 * HW;

    floatx4 acc[4][4];   // [channel group g][n-tile]
    #pragma unroll
    for (int g = 0; g < 4; ++g)
        #pragma unroll
        for (int n = 0; n < 4; ++n) {
            floatx4 z = {0.f, 0.f, 0.f, 0.f};
            acc[g][n] = z;
        }

    const int sp  = tid & 63;   // staging pixel
    const int scg = tid >> 6;   // staging c-group (16 channels each)

    for (int kt = 0; kt < 4; ++kt) {
        const int c0 = kt * 64;
        if (kt) __syncthreads();

        // ---- stage W tile: [256 o][64 k] bf16, b128 copies from pre-converted wb ----
        #pragma unroll
        for (int i = 0; i < 8; ++i) {
            int idx  = i * 256 + tid;       // 2048 chunks of 8 bf16
            int o    = idx >> 3;
            int koff = (idx & 7) * 8;
            ushort8_t v = *reinterpret_cast<const ushort8_t*>(wb + o * 256 + c0 + koff);
            *reinterpret_cast<ushort8_t*>(&ws_s[o * LDS_W + koff]) = v;
        }

        // ---- stage X tile transposed: global [c][p] fp32 -> LDS [p][c] bf16 ----
        {
            const float* xsrc = xb + (size_t)(c0 + scg * 16) * HW + p0 + sp;
            #pragma unroll
            for (int j = 0; j < 4; ++j) {
                ushort4_t v;
                #pragma unroll
                for (int e = 0; e < 4; ++e)
                    v[e] = f2bf(xsrc[(size_t)(j * 4 + e) * HW]);
                *reinterpret_cast<ushort4_t*>(&xs_s[sp * LDS_W + scg * 16 + j * 4]) = v;
            }
        }
        __syncthreads();

        // ---- MFMA: per wave 4 m-tiles x 4 n-tiles x (BK=64 -> 2 k-chunks) ----
        const int lrow = lane & 15;
        const int lk   = (lane >> 4) * 8;
        #pragma unroll
        for (int kc = 0; kc < 2; ++kc) {
            bf16x8 af[4], bfr[4];
            #pragma unroll
            for (int g = 0; g < 4; ++g)
                af[g] = *reinterpret_cast<const bf16x8*>(
                    &ws_s[(g * 64 + wv * 16 + lrow) * LDS_W + kc * 32 + lk]);
            #pragma unroll
            for (int n = 0; n < 4; ++n)
                bfr[n] = *reinterpret_cast<const bf16x8*>(
                    &xs_s[(n * 16 + lrow) * LDS_W + kc * 32 + lk]);
            #pragma unroll
            for (int g = 0; g < 4; ++g)
                #pragma unroll
                for (int n = 0; n < 4; ++n)
                    acc[g][n] = __builtin_amdgcn_mfma_f32_16x16x32_bf16(af[g], bfr[n], acc[g][n], 0, 0, 0);
        }
    }

    // ---- fused lifting epilogue (lane-local) ----
    // C/D map: col = lane&15 (pixel within n-tile), row = 4*(lane>>4)+reg (channel within m-tile)
    const int lrow = lane & 15;
    const int lgr  = lane >> 4;
    #pragma unroll
    for (int ri = 0; ri < 4; ++ri) {
        const int q = wv * 16 + lgr * 4 + ri;     // 0..63
        const float lv0 = lp_v[2 * q], lv1 = lp_v[2 * q + 1];
        const float hv0 = hp_v[2 * q], hv1 = hp_v[2 * q + 1];
        const float lh0 = lp_h[2 * q], lh1 = lp_h[2 * q + 1];
        const float hh0 = hp_h[2 * q], hh1 = hp_h[2 * q + 1];
        float* outq = out + (size_t)(bb * 64 + q) * 65536;   // [256][256] plane
        #pragma unroll
        for (int n = 0; n < 4; ++n) {
            const int p = p0 + n * 16 + lrow;
            const int h = p >> 7;
            const int w = p & 127;
            const float a  = acc[0][n][ri];
            const float b2 = acc[1][n][ri];
            const float c2 = acc[2][n][ri];
            const float d2 = acc[3][n][ri];
            const float xl0 = lv0 * a + lv1 * b2;   // x_l even output row
            const float xl1 = hv0 * a + hv1 * b2;   // x_l odd output row
            const float xh0 = lv0 * c2 + lv1 * d2;  // x_h even
            const float xh1 = hv0 * c2 + hv1 * d2;  // x_h odd
            float2 r0 = make_float2(lh0 * xl0 + lh1 * xh0, hh0 * xl0 + hh1 * xh0);
            float2 r1 = make_float2(lh0 * xl1 + lh1 * xh1, hh0 * xl1 + hh1 * xh1);
            *reinterpret_cast<float2*>(outq + (size_t)(2 * h) * 256 + 2 * w)     = r0;
            *reinterpret_cast<float2*>(outq + (size_t)(2 * h + 1) * 256 + 2 * w) = r1;
        }
    }
}

extern "C" void kernel_launch(void* const* d_in, const int* in_sizes, int n_in,
                              void* d_out, int out_size, void* d_ws, size_t ws_size,
                              hipStream_t stream) {
    const float* x   = (const float*)d_in[0];
    const float* w   = (const float*)d_in[1];
    const float* lpv = (const float*)d_in[2];
    const float* hpv = (const float*)d_in[3];
    const float* lph = (const float*)d_in[4];
    const float* hph = (const float*)d_in[5];
    float* outp = (float*)d_out;
    unsigned short* wb = (unsigned short*)d_ws;   // 128 KB bf16 weights

    wconv_kernel<<<dim3(256), dim3(256), 0, stream>>>(w, wb);
    fused_gemm_lift<<<dim3(4096), dim3(256), 0, stream>>>(x, wb, lpv, hpv, lph, hph, outp);
}